// Round 10
// baseline (955.709 us; speedup 1.0000x reference)
//
#include <hip/hip_runtime.h>
#include <cstdint>
#include <cstddef>
#include <math.h>

#define LC 1.44269504088896340736f   // log2(e)

__device__ __forceinline__ float rl_(float v, int k) {
    return __int_as_float(__builtin_amdgcn_readlane(__float_as_int(v), k));
}
__device__ __forceinline__ float bp_(float v, int addr4) {
    return __int_as_float(__builtin_amdgcn_ds_bpermute(addr4, __float_as_int(v)));
}
#define SZ_(v, pat) __int_as_float(__builtin_amdgcn_ds_swizzle(__float_as_int(v), (pat)))

__device__ __forceinline__ float sigm_(float u) {
    return __fdividef(1.f, 1.f + exp2f(-LC * u));
}
__device__ __forceinline__ float tanh_(float u) {
    return fmaf(-2.f, __fdividef(1.f, 1.f + exp2f((2.f * LC) * u)), 1.f);
}
__device__ __forceinline__ void ld18_(float* d, const float* s) {
    *(float4*)&d[0]  = *(const float4*)&s[0];
    *(float4*)&d[4]  = *(const float4*)&s[4];
    *(float4*)&d[8]  = *(const float4*)&s[8];
    *(float4*)&d[12] = *(const float4*)&s[12];
    d[16] = s[16]; d[17] = s[17];
}

// 3-wave pipeline per batch row (roles rotated across blocks):
//  G: GRU recurrence (early-bp) + LSTM input proj (same readlanes)   xaR -> xlR
//  L: LSTM recurrence (early-bp) + FC                                xlR(lag 16) -> out
//  X: x staging + GRU input projection (1 window ahead)              -> xaR
__global__ __launch_bounds__(192) void rnn_fused10(
    const float* __restrict__ x,
    const float* __restrict__ gWih, const float* __restrict__ gWhh,
    const float* __restrict__ gbih, const float* __restrict__ gbhh,
    const float* __restrict__ lWih, const float* __restrict__ lWhh,
    const float* __restrict__ lbih, const float* __restrict__ lbhh,
    const float* __restrict__ fcW, const float* __restrict__ fcb,
    float* __restrict__ out)
{
    const int tid  = threadIdx.x;
    const int wid  = tid >> 6;
    const int lane = tid & 63;
    const int b    = blockIdx.x;
    const int role = (wid + b) % 3;

    __shared__ __align__(16) float xaR[16][64];   // GRU input proj ring (slot = t & 15)
    __shared__ __align__(16) float xlR[32][80];   // LSTM input proj ring (slot = u & 31)
    __shared__ __align__(16) float xst[2][8][20]; // staged x window (X-private)

    const float* xb   = x   + (size_t)b * (1024 * 18);
    float*       outp = out + (size_t)b * 1024;

    const bool sec  = (lane >= 54) && (lane < 62);
    const int  rg   = (lane < 54) ? lane : 0;
    const int  rsec = sec ? (64 + lane - 54) : 64;

    if (role == 2) {
        // ---------------- X: x staging + GRU input projection ----------------
        float wX[18];
        #pragma unroll
        for (int k = 0; k < 18; k++) wX[k] = (lane < 54) ? gWih[rg * 18 + k] : 0.f;
        const float bX = (lane < 54) ? gbih[rg] : 0.f;

        const int j0 = lane, j1 = lane + 64, j2 = lane + 128;
        const int r0 = j0 / 18, c0 = j0 % 18;
        const int r1 = j1 / 18, c1 = j1 % 18;
        const int r2 = j2 / 18, c2 = j2 % 18;

        // prologue: land window 0, xa window 0, prefetch window 1
        float p0 = xb[j0], p1 = xb[j1], p2 = (lane < 16) ? xb[j2] : 0.f;
        xst[0][r0][c0] = p0; xst[0][r1][c1] = p1; if (lane < 16) xst[0][r2][c2] = p2;
        __builtin_amdgcn_wave_barrier();
        #pragma unroll
        for (int j = 0; j < 8; j++) {
            float xr[18]; ld18_(xr, &xst[0][j][0]);
            float a0 = bX, a1 = 0.f;
            #pragma unroll
            for (int k = 0; k < 18; k += 2) { a0 = fmaf(wX[k], xr[k], a0); a1 = fmaf(wX[k+1], xr[k+1], a1); }
            xaR[j][lane] = a0 + a1;
        }
        p0 = xb[144 + j0]; p1 = xb[144 + j1]; if (lane < 16) p2 = xb[144 + j2];

        for (int p = 0; p < 131; p++) {
            __syncthreads();
            if (p <= 126) {
                const int bu = (p + 1) & 1;
                xst[bu][r0][c0] = p0; xst[bu][r1][c1] = p1; if (lane < 16) xst[bu][r2][c2] = p2;
                if (p + 2 <= 127) {
                    const float* xw = xb + (size_t)(p + 2) * 144;
                    p0 = xw[j0]; p1 = xw[j1]; if (lane < 16) p2 = xw[j2];
                }
                __builtin_amdgcn_wave_barrier();
                const int s1 = ((p + 1) * 8) & 15;
                #pragma unroll
                for (int j = 0; j < 8; j++) {
                    float xr[18]; ld18_(xr, &xst[bu][j][0]);
                    float a0 = bX, a1 = 0.f;
                    #pragma unroll
                    for (int k = 0; k < 18; k += 2) { a0 = fmaf(wX[k], xr[k], a0); a1 = fmaf(wX[k+1], xr[k+1], a1); }
                    xaR[s1 + j][lane] = a0 + a1;
                }
            }
        }
    } else if (role == 0) {
        // ---------------- G: GRU recurrence (early-bp) + LSTM input proj ----------------
        float wG[18], wP[18], wS[18];
        #pragma unroll
        for (int k = 0; k < 18; k++) {
            wG[k] = (lane < 54) ? gWhh[rg * 18 + k] : 0.f;
            wP[k] = lWih[lane * 18 + k];                     // LSTM Wih rows 0..63
            wS[k] = sec ? lWih[rsec * 18 + k] : 0.f;         // rows 64..71
        }
        const float bG = (lane < 54) ? gbhh[rg] : 0.f;
        const float bP = lbih[lane];
        const float bS = sec ? lbih[rsec] : 0.f;

        const int ibx = ((lane + 36) & 63) << 2;   // n-row preact -> r-lane j
        const int ibz = ((lane + 18) & 63) << 2;   // z_j -> lane j

        float myh = 0.f;

        for (int p = 0; p < 131; p++) {
            __syncthreads();
            if (p <= 127) {
                const int base = p * 8;
                const int s0   = base & 15;
                #pragma unroll
                for (int j = 0; j < 8; j++) {
                    const float xa = xaR[s0 + j][lane];
                    // 3 dots off the same 18 readlane broadcasts of h[t-1]
                    float a0 = bG, a1 = 0.f, p0 = bP, p1 = 0.f, q0 = bS, q1 = 0.f;
                    #pragma unroll
                    for (int k = 0; k < 18; k += 2) {
                        const float s_0 = rl_(myh, k), s_1 = rl_(myh, k + 1);
                        a0 = fmaf(wG[k], s_0, a0); a1 = fmaf(wG[k+1], s_1, a1);
                        p0 = fmaf(wP[k], s_0, p0); p1 = fmaf(wP[k+1], s_1, p1);
                        q0 = fmaf(wS[k], s_0, q0); q1 = fmaf(wS[k+1], s_1, q1);
                    }
                    const float ha = a0 + a1;
                    // LSTM input proj of h[t-1] -> ring slot t-1
                    const int sl = (base + j - 1) & 31;
                    xlR[sl][lane] = p0 + p1;
                    if (sec) xlR[sl][64 + (lane - 54)] = q0 + q1;
                    // GRU nonlinear, early-bp (n computed locally on r-lane)
                    const float bpx = bp_(xa, ibx);              // xa_n[j] -> lane j
                    const float bph = bp_(ha, ibx);              // ha_n[j] -> lane j
                    const float sg  = sigm_(xa + ha);            // r on 0..17, z on 18..35
                    const float zz  = bp_(sg, ibz);              // z_j -> lane j
                    const float nv  = tanh_(fmaf(sg, bph, bpx)); // n_j (sg here = r_j)
                    myh = fmaf(zz, myh - nv, nv);                // lanes>=18: finite garbage
                }
            } else if (p == 128) {
                // epilogue: LSTM input proj for t = 1023
                float p0 = bP, p1 = 0.f, q0 = bS, q1 = 0.f;
                #pragma unroll
                for (int k = 0; k < 18; k += 2) {
                    const float s_0 = rl_(myh, k), s_1 = rl_(myh, k + 1);
                    p0 = fmaf(wP[k], s_0, p0); p1 = fmaf(wP[k+1], s_1, p1);
                    q0 = fmaf(wS[k], s_0, q0); q1 = fmaf(wS[k+1], s_1, q1);
                }
                xlR[1023 & 31][lane] = p0 + p1;
                if (sec) xlR[1023 & 31][64 + (lane - 54)] = q0 + q1;
            }
        }
    } else {
        // ---------------- L: LSTM recurrence (early-bp) + FC ----------------
        float wL[18], wL2[18];
        #pragma unroll
        for (int k = 0; k < 18; k++) {
            wL[k]  = lWhh[lane * 18 + k];
            wL2[k] = sec ? lWhh[rsec * 18 + k] : 0.f;
        }
        const float bL  = lbhh[lane];
        const float bL2 = sec ? lbhh[rsec] : 0.f;

        const int ibf  = ((lane + 18) & 63) << 2;   // pre_f -> lane j
        const int ibg  = ((lane + 36) & 63) << 2;   // pre_g -> lane j
        const int ibo1 = ((lane + 54) & 63) << 2;   // pre_o units 0..9
        const int ibo2 = ((lane + 44) & 63) << 2;   // pre_o units 10..17 (sec lanes)

        const float fcw  = (lane < 18) ? fcW[lane] : 0.f;
        const float fcbv = fcb[0];

        float myc = 0.f, myhl = 0.f;
        float o0 = 0.f, o1 = 0.f, o2 = 0.f, o3 = 0.f;

        for (int p = 0; p < 131; p++) {
            __syncthreads();
            if (p >= 2 && p <= 129) {
                const int base = (p - 2) * 8;
                #pragma unroll
                for (int j = 0; j < 8; j++) {
                    const int sl = (base + j) & 31;
                    const float xl  = xlR[sl][lane];
                    const float xl2 = xlR[sl][64 + ((lane - 54) & 7)];
                    float a0 = bL, a1 = 0.f, c0 = bL2, c1 = 0.f;
                    #pragma unroll
                    for (int k = 0; k < 18; k += 2) {
                        const float s_0 = rl_(myhl, k), s_1 = rl_(myhl, k + 1);
                        a0 = fmaf(wL[k],  s_0, a0); a1 = fmaf(wL[k+1],  s_1, a1);
                        c0 = fmaf(wL2[k], s_0, c0); c1 = fmaf(wL2[k+1], s_1, c1);
                    }
                    const float pv  = xl + a0 + a1;          // preact rows 0..63
                    const float pv2 = xl2 + c0 + c1;         // preact rows 64..71 (sec lanes)
                    const float bpf = bp_(pv,  ibf);
                    const float bpg = bp_(pv,  ibg);
                    const float bo1 = bp_(pv,  ibo1);
                    const float bo2 = bp_(pv2, ibo2);
                    const float po  = (lane < 10) ? bo1 : bo2;
                    const float iv  = sigm_(pv);             // i preact local (lanes 0..17)
                    const float fv_ = sigm_(bpf);
                    const float gv  = tanh_(bpg);
                    const float ov_ = sigm_(po);
                    myc  = fmaf(fv_, myc, iv * gv);
                    myhl = ov_ * tanh_(myc);
                    // FC (lanes >= 18 contribute 0)
                    float fv = fcw * myhl;
                    fv += SZ_(fv, 0x041F); fv += SZ_(fv, 0x081F);
                    fv += SZ_(fv, 0x101F); fv += SZ_(fv, 0x201F); fv += SZ_(fv, 0x401F);
                    const float ov = fv + fcbv;
                    if ((j & 3) == 0) o0 = ov; else if ((j & 3) == 1) o1 = ov;
                    else if ((j & 3) == 2) o2 = ov; else o3 = ov;
                    if ((j & 3) == 3 && lane == 0) {
                        float4 vv; vv.x = o0; vv.y = o1; vv.z = o2; vv.w = o3;
                        *reinterpret_cast<float4*>(outp + base + j - 3) = vv;
                    }
                }
            }
        }
    }
}

extern "C" void kernel_launch(void* const* d_in, const int* in_sizes, int n_in,
                              void* d_out, int out_size, void* d_ws, size_t ws_size,
                              hipStream_t stream)
{
    (void)d_ws; (void)ws_size; (void)in_sizes; (void)n_in; (void)out_size;
    const float* xx   = (const float*)d_in[0];
    const float* gWih = (const float*)d_in[1];
    const float* gWhh = (const float*)d_in[2];
    const float* gbih = (const float*)d_in[3];
    const float* gbhh = (const float*)d_in[4];
    const float* lWih = (const float*)d_in[5];
    const float* lWhh = (const float*)d_in[6];
    const float* lbih = (const float*)d_in[7];
    const float* lbhh = (const float*)d_in[8];
    const float* fcW  = (const float*)d_in[9];
    const float* fcb  = (const float*)d_in[10];
    float* outp = (float*)d_out;

    dim3 grid(1024), block(192);
    hipLaunchKernelGGL(rnn_fused10, grid, block, 0, stream,
                       xx, gWih, gWhh, gbih, gbhh,
                       lWih, lWhh, lbih, lbhh, fcW, fcb, outp);
}

// Round 11
// 577.935 us; speedup vs baseline: 1.6537x; 1.6537x over previous
//
#include <hip/hip_runtime.h>
#include <cstdint>
#include <cstddef>
#include <math.h>

#define LC 1.44269504088896340736f   // log2(e)

typedef float f2 __attribute__((ext_vector_type(2)));

__device__ __forceinline__ float rl_(float v, int k) {
    return __int_as_float(__builtin_amdgcn_readlane(__float_as_int(v), k));
}
__device__ __forceinline__ float bp_(float v, int addr4) {
    return __int_as_float(__builtin_amdgcn_ds_bpermute(addr4, __float_as_int(v)));
}
#define SZ_(v, pat) __int_as_float(__builtin_amdgcn_ds_swizzle(__float_as_int(v), (pat)))

__device__ __forceinline__ float sigm_(float u) {
    return __fdividef(1.f, 1.f + exp2f(-LC * u));
}
__device__ __forceinline__ float tanh_(float u) {
    return fmaf(-2.f, __fdividef(1.f, 1.f + exp2f((2.f * LC) * u)), 1.f);
}
// packed 2xf32 FMA: acc += w * h (per 32-bit half)
__device__ __forceinline__ void pk_(f2& acc, f2 w, f2 h) {
    asm("v_pk_fma_f32 %0, %1, %2, %0" : "+v"(acc) : "v"(w), "v"(h));
}
// 18 floats (16B-aligned source) -> 9 f2 pairs
__device__ __forceinline__ void ld9p_(f2* d, const float* s) {
    *(float4*)&d[0] = *(const float4*)&s[0];
    *(float4*)&d[2] = *(const float4*)&s[4];
    *(float4*)&d[4] = *(const float4*)&s[8];
    *(float4*)&d[6] = *(const float4*)&s[12];
    d[8] = *(const f2*)&s[16];
}
__device__ __forceinline__ void ld18_(float* d, const float* s) {
    *(float4*)&d[0]  = *(const float4*)&s[0];
    *(float4*)&d[4]  = *(const float4*)&s[4];
    *(float4*)&d[8]  = *(const float4*)&s[8];
    *(float4*)&d[12] = *(const float4*)&s[12];
    d[16] = s[16]; d[17] = s[17];
}

// 4-wave pipeline per batch row (roles rotated across blocks):
//  G: GRU recurrence (readlane h-broadcast)       xaR -> hR
//  P: LSTM input projection (LDS broadcast + pk)  hR(lag 8) -> xlR
//  L: LSTM recurrence (no FC)                     xlR(lag 16) -> hlR
//  X: x staging + GRU input proj (pk) + FC        hlR(lag 24) -> out
__global__ __launch_bounds__(256, 4) void rnn_fused11(
    const float* __restrict__ x,
    const float* __restrict__ gWih, const float* __restrict__ gWhh,
    const float* __restrict__ gbih, const float* __restrict__ gbhh,
    const float* __restrict__ lWih, const float* __restrict__ lWhh,
    const float* __restrict__ lbih, const float* __restrict__ lbhh,
    const float* __restrict__ fcW, const float* __restrict__ fcb,
    float* __restrict__ out)
{
    const int tid  = threadIdx.x;
    const int wid  = tid >> 6;
    const int lane = tid & 63;
    const int b    = blockIdx.x;
    const int role = (wid + b) & 3;

    __shared__ __align__(16) float xaR[16][64];   // GRU input proj ring (slot = t & 15)
    __shared__ __align__(16) float hR [16][64];   // GRU h ring
    __shared__ __align__(16) float xlR[16][80];   // LSTM input proj ring
    __shared__ __align__(16) float hlR[16][64];   // LSTM h ring (for FC on X)
    __shared__ __align__(16) float xst[2][8][20]; // staged x window (X-private)

    const float* xb   = x   + (size_t)b * (1024 * 18);
    float*       outp = out + (size_t)b * 1024;

    const bool sec  = (lane >= 54) && (lane < 62);
    const int  rg   = (lane < 54) ? lane : 0;
    const int  rsec = sec ? (64 + lane - 54) : 64;

    if (role == 3) {
        // ---------------- X: x staging + GRU input proj (pk) + FC ----------------
        f2 wX2[9];
        #pragma unroll
        for (int i = 0; i < 9; i++) {
            wX2[i].x = (lane < 54) ? gWih[rg * 18 + 2 * i]     : 0.f;
            wX2[i].y = (lane < 54) ? gWih[rg * 18 + 2 * i + 1] : 0.f;
        }
        const float bX   = (lane < 54) ? gbih[rg] : 0.f;
        const float fcw  = (lane < 18) ? fcW[lane] : 0.f;
        const float fcbv = fcb[0];

        const int j0 = lane, j1 = lane + 64, j2 = lane + 128;
        const int r0 = j0 / 18, c0 = j0 % 18;
        const int r1 = j1 / 18, c1 = j1 % 18;
        const int r2 = j2 / 18, c2 = j2 % 18;

        float o0 = 0.f, o1 = 0.f, o2 = 0.f, o3 = 0.f;

        // prologue: land window 0, xa window 0, prefetch window 1
        float p0 = xb[j0], p1 = xb[j1], p2 = (lane < 16) ? xb[j2] : 0.f;
        xst[0][r0][c0] = p0; xst[0][r1][c1] = p1; if (lane < 16) xst[0][r2][c2] = p2;
        __builtin_amdgcn_wave_barrier();
        #pragma unroll
        for (int j = 0; j < 8; j++) {
            __align__(16) f2 xv[10];
            ld9p_(xv, &xst[0][j][0]);
            f2 ax; ax.x = bX; ax.y = 0.f;
            #pragma unroll
            for (int i = 0; i < 9; i++) pk_(ax, wX2[i], xv[i]);
            xaR[j][lane] = ax.x + ax.y;
        }
        p0 = xb[144 + j0]; p1 = xb[144 + j1]; if (lane < 16) p2 = xb[144 + j2];

        for (int p = 0; p < 131; p++) {
            __syncthreads();
            if (p <= 126) {
                const int bu = (p + 1) & 1;
                xst[bu][r0][c0] = p0; xst[bu][r1][c1] = p1; if (lane < 16) xst[bu][r2][c2] = p2;
                if (p + 2 <= 127) {
                    const float* xw = xb + (size_t)(p + 2) * 144;
                    p0 = xw[j0]; p1 = xw[j1]; if (lane < 16) p2 = xw[j2];
                }
                __builtin_amdgcn_wave_barrier();
                const int s1 = ((p + 1) * 8) & 15;
                #pragma unroll
                for (int j = 0; j < 8; j++) {
                    __align__(16) f2 xv[10];
                    ld9p_(xv, &xst[bu][j][0]);
                    f2 ax; ax.x = bX; ax.y = 0.f;
                    #pragma unroll
                    for (int i = 0; i < 9; i++) pk_(ax, wX2[i], xv[i]);
                    xaR[s1 + j][lane] = ax.x + ax.y;
                }
            }
            if (p >= 3) {
                const int base = (p - 3) * 8;
                const int s    = base & 15;
                #pragma unroll
                for (int j = 0; j < 8; j++) {
                    const float hlv = hlR[s + j][lane];
                    float fv = fcw * hlv;
                    fv += SZ_(fv, 0x041F); fv += SZ_(fv, 0x081F);
                    fv += SZ_(fv, 0x101F); fv += SZ_(fv, 0x201F); fv += SZ_(fv, 0x401F);
                    const float ov = fv + fcbv;
                    if ((j & 3) == 0) o0 = ov; else if ((j & 3) == 1) o1 = ov;
                    else if ((j & 3) == 2) o2 = ov; else o3 = ov;
                    if ((j & 3) == 3 && lane == 0) {
                        float4 vv; vv.x = o0; vv.y = o1; vv.z = o2; vv.w = o3;
                        *reinterpret_cast<float4*>(outp + base + j - 3) = vv;
                    }
                }
            }
        }
    } else if (role == 0) {
        // ---------------- G: GRU recurrence ----------------
        float wG[18];
        #pragma unroll
        for (int k = 0; k < 18; k++) wG[k] = (lane < 54) ? gWhh[rg * 18 + k] : 0.f;
        const float bG = (lane < 54) ? gbhh[rg] : 0.f;

        const int i1b = ((lane + 18) & 63) << 2;   // z_j -> lane j
        const int i2b = ((lane + 36) & 63) << 2;   // n_j -> lane j
        const int i3b = ((lane + 28) & 63) << 2;   // r_j -> n-lane 36+j

        float myh = 0.f;

        for (int p = 0; p < 131; p++) {
            __syncthreads();
            if (p <= 127) {
                const int s0 = (p * 8) & 15;
                #pragma unroll
                for (int j = 0; j < 8; j++) {
                    const float xa = xaR[s0 + j][lane];
                    float a0 = bG, a1 = 0.f;
                    #pragma unroll
                    for (int k = 0; k < 18; k += 2) {
                        const float s_0 = rl_(myh, k), s_1 = rl_(myh, k + 1);
                        a0 = fmaf(wG[k], s_0, a0); a1 = fmaf(wG[k+1], s_1, a1);
                    }
                    const float ha = a0 + a1;
                    const float sg = sigm_(xa + ha);
                    const float rv = bp_(sg, i3b);
                    const float tn = tanh_(fmaf(rv, ha, xa));
                    const float zz = bp_(sg, i1b);
                    const float nn = bp_(tn, i2b);
                    myh = fmaf(zz, myh - nn, nn);          // lanes >= 18: finite garbage
                    hR[s0 + j][lane] = myh;
                }
            }
        }
    } else if (role == 1) {
        // ---------------- P: LSTM input projection (LDS broadcast + pk) ----------------
        f2 wP2[9], wS2[9];
        #pragma unroll
        for (int i = 0; i < 9; i++) {
            wP2[i].x = lWih[lane * 18 + 2 * i];
            wP2[i].y = lWih[lane * 18 + 2 * i + 1];
            wS2[i].x = sec ? lWih[rsec * 18 + 2 * i]     : 0.f;
            wS2[i].y = sec ? lWih[rsec * 18 + 2 * i + 1] : 0.f;
        }
        const float bP = lbih[lane];
        const float bS = sec ? lbih[rsec] : 0.f;

        for (int p = 0; p < 131; p++) {
            __syncthreads();
            if (p >= 1 && p <= 128) {
                const int s0 = ((p - 1) * 8) & 15;
                #pragma unroll
                for (int j = 0; j < 8; j++) {
                    __align__(16) f2 hv[10];
                    ld9p_(hv, &hR[s0 + j][0]);             // broadcast reads of h[0..17]
                    f2 aP; aP.x = bP; aP.y = 0.f;
                    f2 aS; aS.x = bS; aS.y = 0.f;
                    #pragma unroll
                    for (int i = 0; i < 9; i++) { pk_(aP, wP2[i], hv[i]); pk_(aS, wS2[i], hv[i]); }
                    xlR[s0 + j][lane] = aP.x + aP.y;
                    if (sec) xlR[s0 + j][64 + (lane - 54)] = aS.x + aS.y;
                }
            }
        }
    } else {
        // ---------------- L: LSTM recurrence (FC moved to X) ----------------
        float wL[18], wL2[18];
        #pragma unroll
        for (int k = 0; k < 18; k++) {
            wL[k]  = lWhh[lane * 18 + k];
            wL2[k] = sec ? lWhh[rsec * 18 + k] : 0.f;
        }
        const float bL  = lbhh[lane];
        const float bL2 = sec ? lbhh[rsec] : 0.f;

        const int i1b = ((lane + 18) & 63) << 2;   // f
        const int i2b = ((lane + 36) & 63) << 2;   // g
        const int i3b = ((lane + 54) & 63) << 2;   // o units 0..9
        const int i4b = ((lane + 44) & 63) << 2;   // o units 10..17 (from lanes 54..61)

        const bool  isg = (lane >= 36) && (lane < 54);
        const float kl  = isg ? (2.f * LC) : LC;
        const float Aa  = isg ? 2.f : 1.f;
        const float Bb  = isg ? -1.f : 0.f;

        float myc = 0.f, myhl = 0.f;

        for (int p = 0; p < 131; p++) {
            __syncthreads();
            if (p >= 2 && p <= 129) {
                const int base = (p - 2) * 8;
                const int s0   = base & 15;
                #pragma unroll
                for (int j = 0; j < 8; j++) {
                    const float xl  = xlR[s0 + j][lane];
                    const float xl2 = xlR[s0 + j][64 + ((lane - 54) & 7)];
                    float a0 = bL, a1 = 0.f, c0 = bL2, c1 = 0.f;
                    #pragma unroll
                    for (int k = 0; k < 18; k += 2) {
                        const float s_0 = rl_(myhl, k), s_1 = rl_(myhl, k + 1);
                        a0 = fmaf(wL[k], s_0, a0); a1 = fmaf(wL[k+1], s_1, a1);
                        c0 = fmaf(wL2[k], s_0, c0); c1 = fmaf(wL2[k+1], s_1, c1);
                    }
                    const float a3 = fmaf(Aa, __fdividef(1.f, 1.f + exp2f(-kl * (xl + a0 + a1))), Bb);
                    const float a4 = sigm_(xl2 + c0 + c1);
                    const float ff = bp_(a3, i1b);
                    const float gg = bp_(a3, i2b);
                    const float oa = bp_(a3, i3b);
                    const float ob = bp_(a4, i4b);
                    const float oo = (lane < 10) ? oa : ob;
                    myc  = fmaf(ff, myc, a3 * gg);         // a3 on lanes<18 = i-gate
                    myhl = oo * tanh_(myc);
                    hlR[s0 + j][lane] = myhl;
                }
            }
        }
    }
}

extern "C" void kernel_launch(void* const* d_in, const int* in_sizes, int n_in,
                              void* d_out, int out_size, void* d_ws, size_t ws_size,
                              hipStream_t stream)
{
    (void)d_ws; (void)ws_size; (void)in_sizes; (void)n_in; (void)out_size;
    const float* xx   = (const float*)d_in[0];
    const float* gWih = (const float*)d_in[1];
    const float* gWhh = (const float*)d_in[2];
    const float* gbih = (const float*)d_in[3];
    const float* gbhh = (const float*)d_in[4];
    const float* lWih = (const float*)d_in[5];
    const float* lWhh = (const float*)d_in[6];
    const float* lbih = (const float*)d_in[7];
    const float* lbhh = (const float*)d_in[8];
    const float* fcW  = (const float*)d_in[9];
    const float* fcb  = (const float*)d_in[10];
    float* outp = (float*)d_out;

    dim3 grid(1024), block(256);
    hipLaunchKernelGGL(rnn_fused11, grid, block, 0, stream,
                       xx, gWih, gWhh, gbih, gbhh,
                       lWih, lWhh, lbih, lbhh, fcW, fcb, outp);
}